// Round 1
// baseline (168.690 us; speedup 1.0000x reference)
//
#include <hip/hip_runtime.h>

// ToBEVReduction: sorted-unique over 27-bit packed coords + segment mean.
// Strategy: 2^27-bit bitmap -> hierarchical popcount scan -> rank = sorted
// segment id. Enumerating set bits gives sorted-unique order directly.
// count==1 segments (~99.85%) are plain stores; rare count>1 & pad rows are
// zeroed then atomically accumulated.

#define NWORDS      (1u << 22)              // 2^27 bits / 32
#define SCAN_BLOCKS 1024
#define WPB         (NWORDS / SCAN_BLOCKS)  // 4096 words per block
#define WPT         (WPB / 256)             // 16 words per thread

__device__ __forceinline__ unsigned key_of(const int* __restrict__ coords, int i) {
    // non-Z dims are columns 0, 2, 3 (Z_DIM = 1); each in [0, 512)
    int c0 = coords[(size_t)i * 4 + 0];
    int c1 = coords[(size_t)i * 4 + 2];
    int c2 = coords[(size_t)i * 4 + 3];
    return ((unsigned)c0 << 18) | ((unsigned)c1 << 9) | (unsigned)c2;
}

__global__ void k_build(const int* __restrict__ coords, unsigned* __restrict__ bitmap, int N) {
    int i = blockIdx.x * blockDim.x + threadIdx.x;
    if (i >= N) return;
    unsigned key = key_of(coords, i);
    atomicOr(&bitmap[key >> 5], 1u << (key & 31u));
}

__global__ void k_scan1(const unsigned* __restrict__ bitmap, unsigned* __restrict__ blockSums) {
    __shared__ unsigned sd[256];
    const uint4* bm = (const uint4*)(bitmap + (size_t)blockIdx.x * WPB + (size_t)threadIdx.x * WPT);
    unsigned s = 0;
#pragma unroll
    for (int k = 0; k < WPT / 4; ++k) {
        uint4 v = bm[k];
        s += __popc(v.x) + __popc(v.y) + __popc(v.z) + __popc(v.w);
    }
    sd[threadIdx.x] = s;
    __syncthreads();
    for (int off = 128; off > 0; off >>= 1) {
        if ((int)threadIdx.x < off) sd[threadIdx.x] += sd[threadIdx.x + off];
        __syncthreads();
    }
    if (threadIdx.x == 0) blockSums[blockIdx.x] = sd[0];
}

__global__ void k_scan2(const unsigned* __restrict__ blockSums, unsigned* __restrict__ blockOffsets) {
    __shared__ unsigned sd[SCAN_BLOCKS];
    int t = threadIdx.x;
    unsigned v = blockSums[t];
    sd[t] = v;
    __syncthreads();
    for (int off = 1; off < SCAN_BLOCKS; off <<= 1) {
        unsigned add = (t >= off) ? sd[t - off] : 0u;
        __syncthreads();
        sd[t] += add;
        __syncthreads();
    }
    blockOffsets[t] = sd[t] - v;  // exclusive
}

__global__ void k_scan3(const unsigned* __restrict__ bitmap,
                        const unsigned* __restrict__ blockOffsets,
                        unsigned* __restrict__ offsets) {
    __shared__ unsigned sd[256];
    size_t base = (size_t)blockIdx.x * WPB + (size_t)threadIdx.x * WPT;
    const uint4* bm = (const uint4*)(bitmap + base);
    unsigned pc[WPT];
    unsigned s = 0;
#pragma unroll
    for (int k = 0; k < WPT / 4; ++k) {
        uint4 v = bm[k];
        pc[k * 4 + 0] = __popc(v.x);
        pc[k * 4 + 1] = __popc(v.y);
        pc[k * 4 + 2] = __popc(v.z);
        pc[k * 4 + 3] = __popc(v.w);
        s += pc[k * 4] + pc[k * 4 + 1] + pc[k * 4 + 2] + pc[k * 4 + 3];
    }
    int t = threadIdx.x;
    sd[t] = s;
    __syncthreads();
    for (int off = 1; off < 256; off <<= 1) {
        unsigned add = (t >= off) ? sd[t - off] : 0u;
        __syncthreads();
        sd[t] += add;
        __syncthreads();
    }
    unsigned run = blockOffsets[blockIdx.x] + sd[t] - s;  // exclusive up to my chunk
#pragma unroll
    for (int k = 0; k < WPT; ++k) {
        offsets[base + k] = run;
        run += pc[k];
    }
}

__global__ void k_fill(float4* __restrict__ outc, int N) {
    int i = blockIdx.x * blockDim.x + threadIdx.x;
    if (i >= N) return;
    outc[i] = make_float4(-1.f, 0.f, 511.f, 511.f);  // pad pattern (overwritten for real rows)
}

__global__ void k_enum(const unsigned* __restrict__ bitmap,
                       const unsigned* __restrict__ offsets,
                       float4* __restrict__ outc) {
    unsigned w = blockIdx.x * blockDim.x + threadIdx.x;
    unsigned bits = bitmap[w];
    if (!bits) return;
    unsigned row = offsets[w];
    while (bits) {
        int b = __ffs(bits) - 1;
        unsigned key = (w << 5) | (unsigned)b;
        float d0 = (float)(key >> 18);
        float d1 = (float)((key >> 9) & 511u);
        float d2 = (float)(key & 511u);
        outc[row] = make_float4(d0, 0.f, d1, d2);
        ++row;
        bits &= bits - 1u;
    }
}

__global__ void k_seg(const int* __restrict__ coords,
                      const unsigned* __restrict__ bitmap,
                      const unsigned* __restrict__ offsets,
                      unsigned* __restrict__ seg,
                      float* __restrict__ cnt, int N) {
    int i = blockIdx.x * blockDim.x + threadIdx.x;
    if (i >= N) return;
    unsigned key = key_of(coords, i);
    unsigned w = key >> 5, b = key & 31u;
    unsigned s = offsets[w] + __popc(bitmap[w] & ((1u << b) - 1u));
    seg[i] = s;
    atomicAdd(&cnt[s], 1.0f);
}

__global__ void k_zero(const float* __restrict__ cnt, float4* __restrict__ feat, int N) {
    int r = blockIdx.x * blockDim.x + threadIdx.x;
    if (r >= N) return;
    if (cnt[r] != 1.0f) {  // pad rows (cnt==0) and multi-count rows
        float4 z = make_float4(0.f, 0.f, 0.f, 0.f);
#pragma unroll
        for (int k = 0; k < 32; ++k) feat[(size_t)r * 32 + k] = z;
    }
}

__global__ void k_scatter(const float4* __restrict__ fin,
                          const unsigned* __restrict__ seg,
                          const float* __restrict__ cnt,
                          float4* __restrict__ fout, int N) {
    int gid = blockIdx.x * blockDim.x + threadIdx.x;
    int elem = gid >> 5;   // 32 threads (float4 each) per 128-float row
    int c4 = gid & 31;
    if (elem >= N) return;
    unsigned s = seg[elem];
    float cv = cnt[s];
    float4 v = fin[(size_t)elem * 32 + c4];
    if (cv == 1.0f) {
        fout[(size_t)s * 32 + c4] = v;
    } else {
        float inv = 1.0f / cv;
        float* p = (float*)&fout[(size_t)s * 32 + c4];
        atomicAdd(p + 0, v.x * inv);
        atomicAdd(p + 1, v.y * inv);
        atomicAdd(p + 2, v.z * inv);
        atomicAdd(p + 3, v.w * inv);
    }
}

extern "C" void kernel_launch(void* const* d_in, const int* in_sizes, int n_in,
                              void* d_out, int out_size, void* d_ws, size_t ws_size,
                              hipStream_t stream) {
    const float4* feat_in = (const float4*)d_in[0];
    const int* coords = (const int*)d_in[1];
    int N = in_sizes[1] / 4;  // 400000

    float* out = (float*)d_out;
    float* out_feat = out;                                    // N*128 floats
    float4* out_coords = (float4*)(out + (size_t)N * 128);    // N*4 floats
    float* out_cnt = out + (size_t)N * 132;                   // N floats

    // Scratch staged in the (not-yet-needed) features output region:
    // every feature row is fully rewritten by k_zero/k_scatter afterwards.
    unsigned* bitmap = (unsigned*)d_out;      // 16 MB
    unsigned* offsets = bitmap + NWORDS;      // 16 MB

    // Small scratch in d_ws (~1.61 MB)
    unsigned* seg = (unsigned*)d_ws;                   // N
    unsigned* blockSums = seg + N;                     // SCAN_BLOCKS
    unsigned* blockOffsets = blockSums + SCAN_BLOCKS;  // SCAN_BLOCKS

    int nb = (N + 255) / 256;

    hipMemsetAsync(bitmap, 0, (size_t)NWORDS * 4, stream);
    hipMemsetAsync(out_cnt, 0, (size_t)N * 4, stream);

    k_build<<<nb, 256, 0, stream>>>(coords, bitmap, N);
    k_scan1<<<SCAN_BLOCKS, 256, 0, stream>>>(bitmap, blockSums);
    k_scan2<<<1, SCAN_BLOCKS, 0, stream>>>(blockSums, blockOffsets);
    k_scan3<<<SCAN_BLOCKS, 256, 0, stream>>>(bitmap, blockOffsets, offsets);
    k_fill<<<nb, 256, 0, stream>>>(out_coords, N);
    k_enum<<<NWORDS / 256, 256, 0, stream>>>(bitmap, offsets, out_coords);
    k_seg<<<nb, 256, 0, stream>>>(coords, bitmap, offsets, seg, out_cnt, N);
    // bitmap/offsets are dead from here; features region gets overwritten.
    k_zero<<<nb, 256, 0, stream>>>(out_cnt, (float4*)out_feat, N);
    k_scatter<<<(int)(((size_t)N * 32 + 255) / 256), 256, 0, stream>>>(
        feat_in, seg, out_cnt, (float4*)out_feat, N);
}